// Round 1
// baseline (301.588 us; speedup 1.0000x reference)
//
#include <hip/hip_runtime.h>
#include <hip/hip_bf16.h>

// Problem geometry (fixed by the reference):
//   x: [B=8, C=32, 4096, 64] fp32  -> flat [256 slabs][N=262144]
//   distance:   perm of N=64^3      (2D order -> 3D voxel order)
//   coordinate: perm of NP=32^3     (pooled 3D -> 2D order)
//   out[bc][j] = max_{e in 2x2x2} x[bc][ distance[ voxel8(coordinate[j], e) ] ]
// out: [256][32768] fp32 (8.4M elements, 32 MiB)

#define N_VOX   262144   // 64^3
#define N_POOL  32768    // 32^3
#define N_BC    256      // B*C
#define JBLOCKS 128      // N_POOL / 256 threads

// ---------------------------------------------------------------------------
// Setup: build srcidx[j][0..7] = the 8 x_flat source indices for output j.
// 32768 threads; trivial cost (~2 MiB of traffic).
__global__ __launch_bounds__(256) void build_idx(const int* __restrict__ distance,
                                                 const int* __restrict__ coordinate,
                                                 int* __restrict__ srcidx) {
    int j = blockIdx.x * 256 + threadIdx.x;
    if (j >= N_POOL) return;
    int p  = coordinate[j];
    int a0 = p >> 10, a1 = (p >> 5) & 31, a2 = p & 31;
    int base = (a0 << 1) * 4096 + (a1 << 1) * 64 + (a2 << 1);
    int4 r0, r1;
    r0.x = distance[base];
    r0.y = distance[base + 1];
    r0.z = distance[base + 64];
    r0.w = distance[base + 65];
    r1.x = distance[base + 4096];
    r1.y = distance[base + 4097];
    r1.z = distance[base + 4160];
    r1.w = distance[base + 4161];
    int4* dst = (int4*)(srcidx + j * 8);
    dst[0] = r0;
    dst[1] = r1;
}

// ---------------------------------------------------------------------------
// Main: one thread per (bc, j). XCD-swizzled so all 128 j-blocks of one bc
// slab land on the same XCD (blockIdx round-robins across the 8 XCDs):
//   lb = blockIdx.x in [0, 32768)
//   xcd  = lb & 7
//   q    = lb >> 3          (per-XCD sequence)
//   slab = q >> 7  (0..31)  -> bc = xcd + 8*slab  (all same-bc blocks on 1 XCD)
//   jb   = q & 127
// Keeps each 1 MiB slab's random 4B gathers hitting one XCD's 4 MiB L2 so the
// 16 uses of each 64B line are L2 hits, not repeated L3/HBM fetches.
__global__ __launch_bounds__(256) void pool_gather(const float* __restrict__ x,
                                                   const int* __restrict__ srcidx,
                                                   float* __restrict__ out) {
    int lb   = blockIdx.x;
    int xcd  = lb & 7;
    int q    = lb >> 3;
    int slab = q >> 7;
    int jb   = q & 127;
    int bc   = xcd + (slab << 3);
    int j    = (jb << 8) + threadIdx.x;

    const float* xb = x + (size_t)bc * N_VOX;
    const int4*  s  = (const int4*)(srcidx + j * 8);
    int4 i0 = s[0];
    int4 i1 = s[1];

    float v0 = fmaxf(xb[i0.x], xb[i0.y]);
    float v1 = fmaxf(xb[i0.z], xb[i0.w]);
    float v2 = fmaxf(xb[i1.x], xb[i1.y]);
    float v3 = fmaxf(xb[i1.z], xb[i1.w]);
    float v  = fmaxf(fmaxf(v0, v1), fmaxf(v2, v3));

    out[(size_t)bc * N_POOL + j] = v;
}

// ---------------------------------------------------------------------------
// Fallback (ws too small for the 1 MiB table): compute indices on the fly.
__global__ __launch_bounds__(256) void pool_gather_fly(const float* __restrict__ x,
                                                       const int* __restrict__ distance,
                                                       const int* __restrict__ coordinate,
                                                       float* __restrict__ out) {
    int lb   = blockIdx.x;
    int xcd  = lb & 7;
    int q    = lb >> 3;
    int slab = q >> 7;
    int jb   = q & 127;
    int bc   = xcd + (slab << 3);
    int j    = (jb << 8) + threadIdx.x;

    int p  = coordinate[j];
    int a0 = p >> 10, a1 = (p >> 5) & 31, a2 = p & 31;
    int base = (a0 << 1) * 4096 + (a1 << 1) * 64 + (a2 << 1);

    const float* xb = x + (size_t)bc * N_VOX;
    float v = xb[distance[base]];
    v = fmaxf(v, xb[distance[base + 1]]);
    v = fmaxf(v, xb[distance[base + 64]]);
    v = fmaxf(v, xb[distance[base + 65]]);
    v = fmaxf(v, xb[distance[base + 4096]]);
    v = fmaxf(v, xb[distance[base + 4097]]);
    v = fmaxf(v, xb[distance[base + 4160]]);
    v = fmaxf(v, xb[distance[base + 4161]]);

    out[(size_t)bc * N_POOL + j] = v;
}

extern "C" void kernel_launch(void* const* d_in, const int* in_sizes, int n_in,
                              void* d_out, int out_size, void* d_ws, size_t ws_size,
                              hipStream_t stream) {
    const float* x          = (const float*)d_in[0];
    const int*   distance   = (const int*)d_in[1];
    const int*   coordinate = (const int*)d_in[2];
    float*       out        = (float*)d_out;

    const size_t tbl_bytes = (size_t)N_POOL * 8 * sizeof(int);  // 1 MiB

    if (ws_size >= tbl_bytes) {
        int* srcidx = (int*)d_ws;
        build_idx<<<JBLOCKS, 256, 0, stream>>>(distance, coordinate, srcidx);
        pool_gather<<<N_BC * JBLOCKS, 256, 0, stream>>>(x, srcidx, out);
    } else {
        pool_gather_fly<<<N_BC * JBLOCKS, 256, 0, stream>>>(x, distance, coordinate, out);
    }
}

// Round 2
// 71.372 us; speedup vs baseline: 4.2256x; 4.2256x over previous
//
#include <hip/hip_runtime.h>
#include <hip/hip_bf16.h>

// Problem geometry (fixed by the reference):
//   x: [B=8, C=32, 4096, 64] fp32  -> flat [256 slabs][N=262144]
//   distance:   perm of N=64^3      (voxel v holds x element distance[v])
//   coordinate: perm of NP=32^3     (output j comes from pooled voxel coordinate[j])
//   out[bc][j] = max over the 2x2x2 block of pooled voxel coordinate[j]
//
// Strategy (R2): SCATTER instead of gather. Every x element i lands in exactly
// one output slot tgt[i] (bijective maps). Precompute tgt (u16, 512 KiB, shared
// by all slabs), then per slab: stream x coalesced, LDS-atomicMax into a
// 128 KiB accumulator, decode + coalesced store. Converts 67M random global
// gathers (R1: 327 us, request-rate bound) into 67M LDS atomics + pure
// streaming HBM traffic (~300 MB => ~50 us roofline).

#define N_VOX   262144   // 64^3
#define N_POOL  32768    // 32^3
#define N_BC    256      // B*C

// Monotone fp32 <-> u32 encoding so unsigned max == float max.
__device__ __forceinline__ unsigned enc_f32(float f) {
    unsigned u = __float_as_uint(f);
    return ((int)u < 0) ? ~u : (u | 0x80000000u);
}
__device__ __forceinline__ float dec_f32(unsigned u) {
    return ((int)u < 0) ? __uint_as_float(u & 0x7fffffffu) : __uint_as_float(~u);
}

// ---------------------------------------------------------------------------
// Setup 1: inv_coordinate (scatter, 32768 threads).
__global__ __launch_bounds__(256) void build_inv(const int* __restrict__ coordinate,
                                                 int* __restrict__ inv) {
    int j = blockIdx.x * 256 + threadIdx.x;
    inv[coordinate[j]] = j;
}

// Setup 2: tgt[distance[v]] = inv_coordinate[pooled(v)]  (u16, 262144 threads).
__global__ __launch_bounds__(256) void build_tgt(const int* __restrict__ distance,
                                                 const int* __restrict__ inv,
                                                 unsigned short* __restrict__ tgt) {
    int v  = blockIdx.x * 256 + threadIdx.x;
    int a0 = v >> 12, a1 = (v >> 6) & 63, a2 = v & 63;
    int p  = (a0 >> 1) * 1024 + (a1 >> 1) * 32 + (a2 >> 1);
    tgt[distance[v]] = (unsigned short)inv[p];
}

// ---------------------------------------------------------------------------
// Main: one 1024-thread workgroup per slab. 128 KiB LDS accumulator.
__global__ __launch_bounds__(1024) void pool_scatter(const float* __restrict__ x,
                                                     const unsigned short* __restrict__ tgt,
                                                     float* __restrict__ out) {
    __shared__ unsigned int acc[N_POOL];  // 128 KiB
    const int tid = threadIdx.x;
    const int bc  = blockIdx.x;

    #pragma unroll
    for (int k = 0; k < N_POOL / 1024; ++k)
        acc[k * 1024 + tid] = 0u;  // encoded "very negative"; overwritten (8 hits/slot)
    __syncthreads();

    const float4*  x4 = (const float4*)(x + (size_t)bc * N_VOX);
    const ushort4* t4 = (const ushort4*)tgt;

    #pragma unroll 4
    for (int it = 0; it < N_VOX / 4 / 1024; ++it) {
        int i = it * 1024 + tid;         // coalesced: lane-consecutive float4/ushort4
        float4  xv = x4[i];
        ushort4 tv = t4[i];
        atomicMax(&acc[tv.x], enc_f32(xv.x));
        atomicMax(&acc[tv.y], enc_f32(xv.y));
        atomicMax(&acc[tv.z], enc_f32(xv.z));
        atomicMax(&acc[tv.w], enc_f32(xv.w));
    }
    __syncthreads();

    float4* o4 = (float4*)(out + (size_t)bc * N_POOL);
    #pragma unroll
    for (int k = 0; k < N_POOL / 4 / 1024; ++k) {
        int j4 = k * 1024 + tid;
        float4 v;
        v.x = dec_f32(acc[j4 * 4 + 0]);
        v.y = dec_f32(acc[j4 * 4 + 1]);
        v.z = dec_f32(acc[j4 * 4 + 2]);
        v.w = dec_f32(acc[j4 * 4 + 3]);
        o4[j4] = v;
    }
}

// ---------------------------------------------------------------------------
// Fallback (ws too small): R1's gather-on-the-fly kernel (correct, slower).
__global__ __launch_bounds__(256) void pool_gather_fly(const float* __restrict__ x,
                                                       const int* __restrict__ distance,
                                                       const int* __restrict__ coordinate,
                                                       float* __restrict__ out) {
    int lb   = blockIdx.x;
    int xcd  = lb & 7;
    int q    = lb >> 3;
    int slab = q >> 7;
    int jb   = q & 127;
    int bc   = xcd + (slab << 3);
    int j    = (jb << 8) + threadIdx.x;

    int p  = coordinate[j];
    int a0 = p >> 10, a1 = (p >> 5) & 31, a2 = p & 31;
    int base = (a0 << 1) * 4096 + (a1 << 1) * 64 + (a2 << 1);

    const float* xb = x + (size_t)bc * N_VOX;
    float v = xb[distance[base]];
    v = fmaxf(v, xb[distance[base + 1]]);
    v = fmaxf(v, xb[distance[base + 64]]);
    v = fmaxf(v, xb[distance[base + 65]]);
    v = fmaxf(v, xb[distance[base + 4096]]);
    v = fmaxf(v, xb[distance[base + 4097]]);
    v = fmaxf(v, xb[distance[base + 4160]]);
    v = fmaxf(v, xb[distance[base + 4161]]);

    out[(size_t)bc * N_POOL + j] = v;
}

extern "C" void kernel_launch(void* const* d_in, const int* in_sizes, int n_in,
                              void* d_out, int out_size, void* d_ws, size_t ws_size,
                              hipStream_t stream) {
    const float* x          = (const float*)d_in[0];
    const int*   distance   = (const int*)d_in[1];
    const int*   coordinate = (const int*)d_in[2];
    float*       out        = (float*)d_out;

    // Workspace layout: [inv_coord: 32768 int = 128 KiB][tgt: 262144 u16 = 512 KiB]
    const size_t need = (size_t)N_POOL * sizeof(int) + (size_t)N_VOX * sizeof(unsigned short);

    if (ws_size >= need) {
        int*            inv = (int*)d_ws;
        unsigned short* tgt = (unsigned short*)((char*)d_ws + (size_t)N_POOL * sizeof(int));
        build_inv<<<N_POOL / 256, 256, 0, stream>>>(coordinate, inv);
        build_tgt<<<N_VOX / 256, 256, 0, stream>>>(distance, inv, tgt);
        pool_scatter<<<N_BC, 1024, 0, stream>>>(x, tgt, out);
    } else {
        pool_gather_fly<<<N_BC * 128, 256, 0, stream>>>(x, distance, coordinate, out);
    }
}

// Round 4
// 61.337 us; speedup vs baseline: 4.9169x; 1.1636x over previous
//
#include <hip/hip_runtime.h>
#include <hip/hip_bf16.h>

// Problem geometry (fixed by the reference):
//   x: [B=8, C=32, 4096, 64] fp32  -> flat [256 slabs][N=262144]
//   distance:   perm of N=64^3      (voxel v holds x element distance[v])
//   coordinate: perm of NP=32^3     (output j comes from pooled voxel coordinate[j])
//   out[bc][j] = max over the 2x2x2 block of pooled voxel coordinate[j]
//
// Strategy (R2->R4): scatter via precomputed u16 target table tgt[i] (every x
// element lands in exactly one output slot; maps are bijective). Per slab:
// stream x coalesced, LDS-atomicMax into a 128 KiB accumulator, decode +
// coalesced store. R4 = R3 with native clang vector types (ext_vector_type)
// so __builtin_nontemporal_load/store compile (HIP_vector_type rejected).

#define N_VOX   262144   // 64^3
#define N_POOL  32768    // 32^3
#define N_BC    256      // B*C

typedef float          f32x4 __attribute__((ext_vector_type(4)));
typedef unsigned int   u32x4 __attribute__((ext_vector_type(4)));
typedef unsigned short u16x4 __attribute__((ext_vector_type(4)));

// Monotone fp32 <-> u32 encoding so unsigned max == float max.
__device__ __forceinline__ unsigned enc_f32(float f) {
    unsigned u = __float_as_uint(f);
    return u ^ (((int)u >> 31) | 0x80000000u);  // 2 VALU ops
}
__device__ __forceinline__ float dec_f32(unsigned u) {
    return __uint_as_float(u ^ (~((int)u >> 31) | 0x80000000u));
}

// ---------------------------------------------------------------------------
// Setup 1: inv_coordinate (scatter, 32768 threads).
__global__ __launch_bounds__(256) void build_inv(const int* __restrict__ coordinate,
                                                 int* __restrict__ inv) {
    int j = blockIdx.x * 256 + threadIdx.x;
    inv[coordinate[j]] = j;
}

// Setup 2: tgt[distance[v]] = inv_coordinate[pooled(v)]  (u16, 262144 threads).
__global__ __launch_bounds__(256) void build_tgt(const int* __restrict__ distance,
                                                 const int* __restrict__ inv,
                                                 unsigned short* __restrict__ tgt) {
    int v  = blockIdx.x * 256 + threadIdx.x;
    int a0 = v >> 12, a1 = (v >> 6) & 63, a2 = v & 63;
    int p  = (a0 >> 1) * 1024 + (a1 >> 1) * 32 + (a2 >> 1);
    tgt[distance[v]] = (unsigned short)inv[p];
}

// ---------------------------------------------------------------------------
// Main: one 1024-thread workgroup per slab. 128 KiB LDS accumulator.
// 64 float4-iterations/thread, chunked 4x, ping-pong double-buffered.
#define CH   4                       // f32x4-iters per chunk
#define NCH  (N_VOX / 4 / 1024 / CH) // 16 chunks

__global__ __launch_bounds__(1024) void pool_scatter(const float* __restrict__ x,
                                                     const unsigned short* __restrict__ tgt,
                                                     float* __restrict__ out) {
    __shared__ unsigned int acc[N_POOL];  // 128 KiB
    const int tid = threadIdx.x;
    const int bc  = blockIdx.x;

    // Vectorized init: 8 x u32x4 stores per thread.
    u32x4* a4i = (u32x4*)acc;
    const u32x4 z4 = {0u, 0u, 0u, 0u};
    #pragma unroll
    for (int k = 0; k < N_POOL / 4 / 1024; ++k)
        a4i[k * 1024 + tid] = z4;
    __syncthreads();

    const f32x4* x4 = (const f32x4*)(x + (size_t)bc * N_VOX);
    const u16x4* t4 = (const u16x4*)tgt;

    f32x4 xa[CH], xb[CH];
    u16x4 ta[CH], tb[CH];

#define LOADC(XV, TV, c)                                                     \
    {                                                                        \
        _Pragma("unroll")                                                    \
        for (int u = 0; u < CH; ++u) {                                       \
            int i = ((c) * CH + u) * 1024 + tid;                             \
            XV[u] = __builtin_nontemporal_load(&x4[i]);                      \
            TV[u] = t4[i];                                                   \
        }                                                                    \
    }

#define PROC(XV, TV)                                                         \
    {                                                                        \
        _Pragma("unroll")                                                    \
        for (int u = 0; u < CH; ++u) {                                       \
            atomicMax(&acc[TV[u].x], enc_f32(XV[u].x));                      \
            atomicMax(&acc[TV[u].y], enc_f32(XV[u].y));                      \
            atomicMax(&acc[TV[u].z], enc_f32(XV[u].z));                      \
            atomicMax(&acc[TV[u].w], enc_f32(XV[u].w));                      \
        }                                                                    \
    }

    LOADC(xa, ta, 0);
    for (int c = 0; c < NCH; c += 2) {
        LOADC(xb, tb, c + 1);
        PROC(xa, ta);
        if (c + 2 < NCH) LOADC(xa, ta, c + 2);
        PROC(xb, tb);
    }
    __syncthreads();

    // Epilogue: u32x4 acc read, decode, nontemporal f32x4 store.
    const u32x4* a4 = (const u32x4*)acc;
    f32x4* o4 = (f32x4*)(out + (size_t)bc * N_POOL);
    #pragma unroll
    for (int k = 0; k < N_POOL / 4 / 1024; ++k) {
        int j4 = k * 1024 + tid;
        u32x4 a = a4[j4];
        f32x4 v;
        v.x = dec_f32(a.x);
        v.y = dec_f32(a.y);
        v.z = dec_f32(a.z);
        v.w = dec_f32(a.w);
        __builtin_nontemporal_store(v, &o4[j4]);
    }
}

// ---------------------------------------------------------------------------
// Fallback (ws too small): gather-on-the-fly kernel (correct, slower).
__global__ __launch_bounds__(256) void pool_gather_fly(const float* __restrict__ x,
                                                       const int* __restrict__ distance,
                                                       const int* __restrict__ coordinate,
                                                       float* __restrict__ out) {
    int lb   = blockIdx.x;
    int xcd  = lb & 7;
    int q    = lb >> 3;
    int slab = q >> 7;
    int jb   = q & 127;
    int bc   = xcd + (slab << 3);
    int j    = (jb << 8) + threadIdx.x;

    int p  = coordinate[j];
    int a0 = p >> 10, a1 = (p >> 5) & 31, a2 = p & 31;
    int base = (a0 << 1) * 4096 + (a1 << 1) * 64 + (a2 << 1);

    const float* xb = x + (size_t)bc * N_VOX;
    float v = xb[distance[base]];
    v = fmaxf(v, xb[distance[base + 1]]);
    v = fmaxf(v, xb[distance[base + 64]]);
    v = fmaxf(v, xb[distance[base + 65]]);
    v = fmaxf(v, xb[distance[base + 4096]]);
    v = fmaxf(v, xb[distance[base + 4097]]);
    v = fmaxf(v, xb[distance[base + 4160]]);
    v = fmaxf(v, xb[distance[base + 4161]]);

    out[(size_t)bc * N_POOL + j] = v;
}

extern "C" void kernel_launch(void* const* d_in, const int* in_sizes, int n_in,
                              void* d_out, int out_size, void* d_ws, size_t ws_size,
                              hipStream_t stream) {
    const float* x          = (const float*)d_in[0];
    const int*   distance   = (const int*)d_in[1];
    const int*   coordinate = (const int*)d_in[2];
    float*       out        = (float*)d_out;

    // Workspace layout: [inv_coord: 32768 int = 128 KiB][tgt: 262144 u16 = 512 KiB]
    const size_t need = (size_t)N_POOL * sizeof(int) + (size_t)N_VOX * sizeof(unsigned short);

    if (ws_size >= need) {
        int*            inv = (int*)d_ws;
        unsigned short* tgt = (unsigned short*)((char*)d_ws + (size_t)N_POOL * sizeof(int));
        build_inv<<<N_POOL / 256, 256, 0, stream>>>(coordinate, inv);
        build_tgt<<<N_VOX / 256, 256, 0, stream>>>(distance, inv, tgt);
        pool_scatter<<<N_BC, 1024, 0, stream>>>(x, tgt, out);
    } else {
        pool_gather_fly<<<N_BC * 128, 256, 0, stream>>>(x, distance, coordinate, out);
    }
}

// Round 5
// 58.940 us; speedup vs baseline: 5.1169x; 1.0407x over previous
//
#include <hip/hip_runtime.h>
#include <hip/hip_bf16.h>

// Problem geometry (fixed by the reference):
//   x: [B=8, C=32, 4096, 64] fp32  -> flat [256 slabs][N=262144]
//   distance:   perm of N=64^3      (voxel v holds x element distance[v])
//   coordinate: perm of NP=32^3     (output j comes from pooled voxel coordinate[j])
//   out[bc][j] = max over the 2x2x2 block of pooled voxel coordinate[j]
//
// Strategy (R2->R5): scatter via precomputed u16 target table tgt[i] (every x
// element lands in exactly one output slot; maps are bijective). Per slab:
// stream x coalesced (nontemporal), LDS-atomicMax into a 128 KiB accumulator,
// decode + coalesced nontemporal store.
// R5: single fused setup kernel (no inv pass), raw s_barrier + lgkmcnt-only
// waits (avoid __syncthreads' vmcnt(0) drain), first load chunk issued before
// LDS init (ramp overlap), CH=8 ping-pong (32 loads in flight).

#define N_VOX   262144   // 64^3
#define N_POOL  32768    // 32^3
#define N_BC    256      // B*C

typedef float          f32x4 __attribute__((ext_vector_type(4)));
typedef unsigned int   u32x4 __attribute__((ext_vector_type(4)));
typedef unsigned short u16x4 __attribute__((ext_vector_type(4)));

// Monotone fp32 <-> u32 encoding so unsigned max == float max.
__device__ __forceinline__ unsigned enc_f32(float f) {
    unsigned u = __float_as_uint(f);
    return u ^ (((int)u >> 31) | 0x80000000u);  // 2 VALU ops
}
__device__ __forceinline__ float dec_f32(unsigned u) {
    return __uint_as_float(u ^ (~((int)u >> 31) | 0x80000000u));
}

// ---------------------------------------------------------------------------
// Fused setup: for each output j, scatter j into the 8 tgt slots of its 2x2x2
// source block. tgt[distance[child(coordinate[j],e)]] = j. Each tgt entry is
// written exactly once (bijections), so plain u16 stores are race-free.
__global__ __launch_bounds__(256) void build_tgt_direct(const int* __restrict__ distance,
                                                        const int* __restrict__ coordinate,
                                                        unsigned short* __restrict__ tgt) {
    int j = blockIdx.x * 256 + threadIdx.x;
    int p = coordinate[j];
    int base = ((p >> 10) << 1) * 4096 + (((p >> 5) & 31) << 1) * 64 + ((p & 31) << 1);
    unsigned short js = (unsigned short)j;
    tgt[distance[base]]        = js;
    tgt[distance[base + 1]]    = js;
    tgt[distance[base + 64]]   = js;
    tgt[distance[base + 65]]   = js;
    tgt[distance[base + 4096]] = js;
    tgt[distance[base + 4097]] = js;
    tgt[distance[base + 4160]] = js;
    tgt[distance[base + 4161]] = js;
}

// ---------------------------------------------------------------------------
// Main: one 1024-thread workgroup per slab. 128 KiB LDS accumulator.
// 64 f32x4-iterations/thread, chunked CH=8, ping-pong double-buffered.
#define CH   8                       // f32x4-iters per chunk
#define NCH  (N_VOX / 4 / 1024 / CH) // 8 chunks

// LDS-only barrier: drain DS ops, then raw s_barrier (no vmcnt(0) drain, so
// in-flight global loads keep flying across the barrier).
__device__ __forceinline__ void lds_barrier() {
    asm volatile("s_waitcnt lgkmcnt(0)" ::: "memory");
    __builtin_amdgcn_s_barrier();
}

__global__ __launch_bounds__(1024) void pool_scatter(const float* __restrict__ x,
                                                     const unsigned short* __restrict__ tgt,
                                                     float* __restrict__ out) {
    __shared__ unsigned int acc[N_POOL];  // 128 KiB
    const int tid = threadIdx.x;
    const int bc  = blockIdx.x;

    const f32x4* x4 = (const f32x4*)(x + (size_t)bc * N_VOX);
    const u16x4* t4 = (const u16x4*)tgt;

    f32x4 xa[CH], xb[CH];
    u16x4 ta[CH], tb[CH];

#define LOADC(XV, TV, c)                                                     \
    {                                                                        \
        _Pragma("unroll")                                                    \
        for (int u = 0; u < CH; ++u) {                                       \
            int i = ((c) * CH + u) * 1024 + tid;                             \
            XV[u] = __builtin_nontemporal_load(&x4[i]);                      \
            TV[u] = t4[i];                                                   \
        }                                                                    \
    }

#define PROC(XV, TV)                                                         \
    {                                                                        \
        _Pragma("unroll")                                                    \
        for (int u = 0; u < CH; ++u) {                                       \
            atomicMax(&acc[TV[u].x], enc_f32(XV[u].x));                      \
            atomicMax(&acc[TV[u].y], enc_f32(XV[u].y));                      \
            atomicMax(&acc[TV[u].z], enc_f32(XV[u].z));                      \
            atomicMax(&acc[TV[u].w], enc_f32(XV[u].w));                      \
        }                                                                    \
    }

    // Issue the first chunk's loads before LDS init: HBM ramp overlaps init.
    LOADC(xa, ta, 0);

    // Vectorized init: 8 x u32x4 stores per thread (encoded "very negative").
    u32x4* a4i = (u32x4*)acc;
    const u32x4 z4 = {0u, 0u, 0u, 0u};
    #pragma unroll
    for (int k = 0; k < N_POOL / 4 / 1024; ++k)
        a4i[k * 1024 + tid] = z4;
    lds_barrier();

    for (int c = 0; c < NCH; c += 2) {
        LOADC(xb, tb, c + 1);
        PROC(xa, ta);
        if (c + 2 < NCH) LOADC(xa, ta, c + 2);
        PROC(xb, tb);
    }
    lds_barrier();

    // Epilogue: u32x4 acc read, decode, nontemporal f32x4 store.
    const u32x4* a4 = (const u32x4*)acc;
    f32x4* o4 = (f32x4*)(out + (size_t)bc * N_POOL);
    #pragma unroll
    for (int k = 0; k < N_POOL / 4 / 1024; ++k) {
        int j4 = k * 1024 + tid;
        u32x4 a = a4[j4];
        f32x4 v;
        v.x = dec_f32(a.x);
        v.y = dec_f32(a.y);
        v.z = dec_f32(a.z);
        v.w = dec_f32(a.w);
        __builtin_nontemporal_store(v, &o4[j4]);
    }
}

// ---------------------------------------------------------------------------
// Fallback (ws too small): gather-on-the-fly kernel (correct, slower).
__global__ __launch_bounds__(256) void pool_gather_fly(const float* __restrict__ x,
                                                       const int* __restrict__ distance,
                                                       const int* __restrict__ coordinate,
                                                       float* __restrict__ out) {
    int lb   = blockIdx.x;
    int xcd  = lb & 7;
    int q    = lb >> 3;
    int slab = q >> 7;
    int jb   = q & 127;
    int bc   = xcd + (slab << 3);
    int j    = (jb << 8) + threadIdx.x;

    int p  = coordinate[j];
    int a0 = p >> 10, a1 = (p >> 5) & 31, a2 = p & 31;
    int base = (a0 << 1) * 4096 + (a1 << 1) * 64 + (a2 << 1);

    const float* xb = x + (size_t)bc * N_VOX;
    float v = xb[distance[base]];
    v = fmaxf(v, xb[distance[base + 1]]);
    v = fmaxf(v, xb[distance[base + 64]]);
    v = fmaxf(v, xb[distance[base + 65]]);
    v = fmaxf(v, xb[distance[base + 4096]]);
    v = fmaxf(v, xb[distance[base + 4097]]);
    v = fmaxf(v, xb[distance[base + 4160]]);
    v = fmaxf(v, xb[distance[base + 4161]]);

    out[(size_t)bc * N_POOL + j] = v;
}

extern "C" void kernel_launch(void* const* d_in, const int* in_sizes, int n_in,
                              void* d_out, int out_size, void* d_ws, size_t ws_size,
                              hipStream_t stream) {
    const float* x          = (const float*)d_in[0];
    const int*   distance   = (const int*)d_in[1];
    const int*   coordinate = (const int*)d_in[2];
    float*       out        = (float*)d_out;

    const size_t need = (size_t)N_VOX * sizeof(unsigned short);  // tgt: 512 KiB

    if (ws_size >= need) {
        unsigned short* tgt = (unsigned short*)d_ws;
        build_tgt_direct<<<N_POOL / 256, 256, 0, stream>>>(distance, coordinate, tgt);
        pool_scatter<<<N_BC, 1024, 0, stream>>>(x, tgt, out);
    } else {
        pool_gather_fly<<<N_BC * 128, 256, 0, stream>>>(x, distance, coordinate, out);
    }
}